// Round 3
// baseline (3027.734 us; speedup 1.0000x reference)
//
#include <hip/hip_runtime.h>
#include <hip/hip_bf16.h>
#include <math.h>

typedef __hip_bfloat16 bf16;
typedef __attribute__((ext_vector_type(8))) short short8;
typedef __attribute__((ext_vector_type(4))) float floatx4;

#define SEQ   128
#define BATCH 64
#define VOCAB 10000
#define HID   1024
#define TAIL  81920000   // SEQ*BATCH*VOCAB, element offset of h_final in d_out
#define PNL   131072     // one hidden panel: 64 rows * 1024 cols * 2B (bf16)

#define MFMA(a,b,c) __builtin_amdgcn_mfma_f32_16x16x32_bf16((a),(b),(c),0,0,0)

// Data path: relaxed agent-scope (sc1) write-through stores + LLC-direct loads.
// Control path: ACQUIRE spin loads (progress-guaranteed: buffer_inv per poll)
//               + RELEASE adds (prior sc1 stores LLC-visible before bump).
#define LDA_U64(p)   __hip_atomic_load((const unsigned long long*)(p), __ATOMIC_RELAXED, __HIP_MEMORY_SCOPE_AGENT)
#define LDAQ_I32(p)  __hip_atomic_load((const int*)(p), __ATOMIC_ACQUIRE, __HIP_MEMORY_SCOPE_AGENT)
#define STA_U32(p,v) __hip_atomic_store((unsigned int*)(p), (v), __ATOMIC_RELAXED, __HIP_MEMORY_SCOPE_AGENT)
#define ADDR_I32(p)  __hip_atomic_fetch_add((int*)(p), 1, __ATOMIC_RELEASE, __HIP_MEMORY_SCOPE_AGENT)

union U16B { unsigned long long u[2]; short8 s; };

__device__ inline unsigned int pack2(float lo, float hi) {
  unsigned short a = __builtin_bit_cast(unsigned short, __float2bfloat16(lo));
  unsigned short b = __builtin_bit_cast(unsigned short, __float2bfloat16(hi));
  return ((unsigned int)b << 16) | (unsigned int)a;
}

__device__ inline void gl_lds16(const bf16* g, bf16* s) {
  __builtin_amdgcn_global_load_lds(
      (const __attribute__((address_space(1))) void*)g,
      (__attribute__((address_space(3))) void*)s, 16, 0, 0);
}

// read element i of an input tensor that is either fp32 (f=1) or bf16 (f=0)
__device__ inline float ld_in(const void* p, size_t i, int f) {
  return f ? ((const float*)p)[i] : __bfloat162float(((const bf16*)p)[i]);
}

// ---------------------------------------------------------------------------
// Detect input dtype. flag[0]=1 -> fp32 inputs, 0 -> bf16.
// Zeroes flag[1]/flag[2]: the c0/c1 step counters for the persistent kernel.
// ---------------------------------------------------------------------------
__global__ __launch_bounds__(256) void detect(const unsigned short* __restrict__ u,
                                              int* __restrict__ flag) {
  __shared__ int smax;
  if (threadIdx.x == 0) smax = 0;
  __syncthreads();
  int mymax = 0;
  for (int i = threadIdx.x * 2; i < 4096; i += 512) {   // even indices only
    int e = (u[i] >> 7) & 0xFF;
    mymax = max(mymax, e);
  }
  atomicMax(&smax, mymax);
  __syncthreads();
  if (threadIdx.x == 0) {
    flag[0] = (smax >= 0xF0) ? 1 : 0;
    flag[1] = 0;                                        // c0 (h0 cohort)
    flag[2] = 0;                                        // c1 (h1 cohort)
  }
}

// ---------------------------------------------------------------------------
__global__ __launch_bounds__(256) void convert_any(const void* __restrict__ src,
                                                   bf16* __restrict__ dst, int n,
                                                   const int* __restrict__ flagp) {
  int f = *flagp;
  for (int i = blockIdx.x * 256 + threadIdx.x; i < n; i += gridDim.x * 256)
    dst[i] = __float2bfloat16(ld_in(src, (size_t)i, f));
}

// initial hidden states -> bf16 panels (slot 0 of H0 ring / H1 triple-buffer)
__global__ __launch_bounds__(256) void init_hidden(const void* __restrict__ src,
                                                   bf16* __restrict__ h0,
                                                   bf16* __restrict__ h1,
                                                   const int* __restrict__ flagp) {
  int f = *flagp;
  int i = blockIdx.x * 256 + threadIdx.x;
  if (i < 65536) {
    h0[i] = __float2bfloat16(ld_in(src, (size_t)i, f));
    h1[i] = __float2bfloat16(ld_in(src, (size_t)(65536 + i), f));
  }
}

// ---------------------------------------------------------------------------
// Transpose the 4 recurrence weight matrices into bf16 [n][k] (K-contiguous).
// Wt layout: z=0 Wx0^T, z=1 Wh0^T, z=2 Wx1^T, z=3 Wh1^T (each 1024x1024).
// ---------------------------------------------------------------------------
__global__ __launch_bounds__(256) void transpose4(const void* __restrict__ Wx,
                                                  const void* __restrict__ Wh,
                                                  bf16* __restrict__ Wt,
                                                  const int* __restrict__ flagp) {
  __shared__ bf16 tile[64][65];
  int f = *flagp;
  int z = blockIdx.z;
  const void* src = (z & 1) ? Wh : Wx;
  size_t loff = (z >> 1) ? (size_t)HID * HID : 0;
  bf16* dst = Wt + (size_t)z * HID * HID;
  int r0 = blockIdx.x * 64, c0 = blockIdx.y * 64;
  int t = threadIdx.x, cc = t & 63, rg = t >> 6;
  #pragma unroll
  for (int i = 0; i < 16; ++i) {
    int r = rg * 16 + i;
    tile[r][cc] = __float2bfloat16(ld_in(src, loff + (size_t)(r0 + r) * HID + c0 + cc, f));
  }
  __syncthreads();
  #pragma unroll
  for (int i = 0; i < 16; ++i) {
    int j = rg * 16 + i;
    dst[(size_t)(c0 + j) * HID + r0 + cc] = tile[cc][j];  // dst[j][k]=src[k][j]
  }
}

// ---------------------------------------------------------------------------
// A0 = emb[tok] @ Wx0 + b0   (fp32 out, [8192][1024]).  m97-style 128x128x32.
// ---------------------------------------------------------------------------
__global__ __launch_bounds__(256) void gemm_a0(
    const int*  __restrict__ tok,    // [8192]
    const bf16* __restrict__ emb,    // [VOCAB][HID] bf16
    const bf16* __restrict__ Wx0t,   // [HID][HID]  (n,k)
    const bf16* __restrict__ b0,     // [HID] bf16
    float* __restrict__ A0)          // [8192][HID]
{
  __shared__ __align__(16) bf16 sA[128 * 32];
  __shared__ __align__(16) bf16 sB[128 * 32];
  int m0 = blockIdx.x * 128, n0 = blockIdx.y * 128;
  int t = threadIdx.x, lane = t & 63, w = t >> 6;
  int wm = (w >> 1) * 64, wn = (w & 1) * 64;
  int quad = lane >> 4, l16 = lane & 15;

  int r0 = t >> 2, kc = t & 3;
  const bf16* ga0 = emb + (size_t)tok[m0 + r0] * HID + kc * 8;
  const bf16* ga1 = emb + (size_t)tok[m0 + r0 + 64] * HID + kc * 8;
  const bf16* gb0 = Wx0t + (size_t)(n0 + r0) * HID + kc * 8;
  const bf16* gb1 = gb0 + (size_t)64 * HID;
  bf16* sa0 = sA + t * 8;  bf16* sa1 = sA + (t + 256) * 8;
  bf16* sb0 = sB + t * 8;  bf16* sb1 = sB + (t + 256) * 8;

  floatx4 acc[4][4];
  #pragma unroll
  for (int j = 0; j < 4; ++j) {
    float bv = __bfloat162float(b0[n0 + wn + j * 16 + l16]);
    #pragma unroll
    for (int i = 0; i < 4; ++i) acc[i][j] = (floatx4){bv, bv, bv, bv};
  }

  for (int kt = 0; kt < 32; ++kt) {
    gl_lds16(ga0, sa0); gl_lds16(ga1, sa1);
    gl_lds16(gb0, sb0); gl_lds16(gb1, sb1);
    ga0 += 32; ga1 += 32; gb0 += 32; gb1 += 32;
    __syncthreads();
    short8 af[4], bfr[4];
    #pragma unroll
    for (int i = 0; i < 4; ++i)
      af[i] = *(const short8*)(sA + (wm + i * 16 + l16) * 32 + quad * 8);
    #pragma unroll
    for (int j = 0; j < 4; ++j)
      bfr[j] = *(const short8*)(sB + (wn + j * 16 + l16) * 32 + quad * 8);
    #pragma unroll
    for (int i = 0; i < 4; ++i)
      #pragma unroll
      for (int j = 0; j < 4; ++j)
        acc[i][j] = MFMA(af[i], bfr[j], acc[i][j]);
    __syncthreads();
  }

  #pragma unroll
  for (int i = 0; i < 4; ++i)
    #pragma unroll
    for (int j = 0; j < 4; ++j)
      #pragma unroll
      for (int r = 0; r < 4; ++r) {
        int row = wm + i * 16 + quad * 4 + r;
        int col = wn + j * 16 + l16;
        A0[(size_t)(m0 + row) * HID + n0 + col] = acc[i][j][r];
      }
}

// ---------------------------------------------------------------------------
// Persistent wavefront:
//   blocks  0..31 (h0, N=32): h0[k]   = tanh(A0[k] + h0[k-1] @ Wh0)
//   blocks 32..95 (h1, N=16): h1[s]   = tanh(h0[s]@Wx1 + h1[s-1]@Wh1 + b1)
// Hidden panels exchanged through LLC via relaxed sc1 write-through stores /
// sc1 loads (no fences on the data path). Control: c0/c1 forward-only
// counters; ACQUIRE spin (progress-guaranteed), RELEASE add (publishes the
// panel). h0 never waits on h1 except the 32-deep H0 ring-reuse guard.
// ---------------------------------------------------------------------------
__global__ __launch_bounds__(256) void wavefront_persist(
    const float* __restrict__ A0,
    const bf16* __restrict__ Wt,      // 4x[1024][1024]: Wx0t,Wh0t,Wx1t,Wh1t
    const bf16* __restrict__ bvecB,   // [2*HID] bf16
    char* __restrict__ H0f,           // 32-slot ring of bf16 panels [64][1024]
    char* __restrict__ H1f,           // 3-slot ring of bf16 panels
    bf16* __restrict__ H1hist,        // [8192][HID] bf16 (for gemm_logits)
    void* __restrict__ outv,
    int* __restrict__ flagp)          // [0]=dtype flag, [1]=c0, [2]=c1
{
  __shared__ short8 sW8[4096];        // 64 KB weight slice, MFMA-native layout
  char* sWb = (char*)sW8;
  const int f = flagp[0];
  int* c0 = flagp + 1;
  int* c1 = flagp + 2;
  char* H1B = (char*)H1hist;
  const int blk = blockIdx.x;
  const int t = threadIdx.x, lane = t & 63, w = t >> 6;
  const int quad = lane >> 4, l16 = lane & 15;
  const int m = w * 16;               // wave w: rows m..m+15
  const bool isH1 = blk >= 32;

  const bf16* Wh0t = Wt + (size_t)1 * HID * HID;
  const bf16* Wx1t = Wt + (size_t)2 * HID * HID;
  const bf16* Wh1t = Wt + (size_t)3 * HID * HID;

  // ---- one-time LDS staging of this block's weight slice(s) ----
  // chunk (row,c16) -> off so hot-loop read is sWb + lane*16 + kt*stride.
  if (!isH1) {
    const int n0 = blk * 32;          // 32 rows of Wh0^T
    #pragma unroll
    for (int i = 0; i < 16; ++i) {
      int idx = i * 256 + t;          // 0..4095
      int row = idx >> 7, c16 = idx & 127;
      short8 v = *(const short8*)(Wh0t + (size_t)(n0 + row) * HID + c16 * 8);
      int off = (c16 >> 2) * 2048 + (row >> 4) * 1024 + (c16 & 3) * 256 + (row & 15) * 16;
      *(short8*)(sWb + off) = v;
    }
  } else {
    const int n0 = (blk - 32) * 16;   // 16 rows each of Wx1^T, Wh1^T
    #pragma unroll
    for (int i = 0; i < 8; ++i) {
      int idx = i * 256 + t;          // 0..2047
      int row = idx >> 7, c16 = idx & 127;
      int off = (c16 >> 2) * 1024 + (c16 & 3) * 256 + (row & 15) * 16;
      *(short8*)(sWb + off)         = *(const short8*)(Wx1t + (size_t)(n0 + row) * HID + c16 * 8);
      *(short8*)(sWb + 32768 + off) = *(const short8*)(Wh1t + (size_t)(n0 + row) * HID + c16 * 8);
    }
  }
  __syncthreads();

  if (!isH1) {
    // ===================== h0 cohort: 32 blocks, 32 cols each ==============
    const int n0 = blk * 32;
    const char* b0p = sWb + lane * 16;          // j=0 cols, kt stride 2048
    const char* b1p = sWb + 1024 + lane * 16;   // j=1 cols
    for (int k = 0; k < 128; ++k) {
      if (t == 0) {
        if (k > 0)   while (LDAQ_I32(c0) < 32 * k)        __builtin_amdgcn_s_sleep(1);
        if (k >= 32) while (LDAQ_I32(c1) < 64 * (k - 31)) __builtin_amdgcn_s_sleep(1);
      }
      __syncthreads();

      // batch-issue all 64 A-fragment loads (LLC, sc1); then A0 addends
      const char* aB = H0f + (size_t)(k & 31) * PNL + (m + l16) * 2048 + quad * 16;
      U16B a[32];
      #pragma unroll
      for (int kt = 0; kt < 32; ++kt) {
        a[kt].u[0] = LDA_U64(aB + kt * 64);
        a[kt].u[1] = LDA_U64(aB + kt * 64 + 8);
      }
      float a0r[2][4];
      #pragma unroll
      for (int j = 0; j < 2; ++j)
        #pragma unroll
        for (int r = 0; r < 4; ++r)
          a0r[j][r] = A0[(size_t)(k * 64 + m + quad * 4 + r) * HID + n0 + j * 16 + l16];

      floatx4 acc0 = {}, acc1 = {};
      #pragma unroll
      for (int kt = 0; kt < 32; ++kt) {
        acc0 = MFMA(a[kt].s, *(const short8*)(b0p + kt * 2048), acc0);
        acc1 = MFMA(a[kt].s, *(const short8*)(b1p + kt * 2048), acc1);
      }

      // epilogue: tanh, pack bf16 pairs, write-through to H0f ring slot k+1
      char* wp = H0f + (size_t)((k + 1) & 31) * PNL;
      #pragma unroll
      for (int j = 0; j < 2; ++j) {
        floatx4 ac = j ? acc1 : acc0;
        #pragma unroll
        for (int r = 0; r < 4; ++r) {
          int row = m + quad * 4 + r, col = n0 + j * 16 + l16;
          float v = tanhf(ac[r] + a0r[j][r]);
          float pv = __shfl_xor(v, 1);
          if (k == 127) {                                        // h_final[0]
            size_t o = (size_t)TAIL + (size_t)row * HID + col;
            if (f) ((float*)outv)[o] = v;
            else   ((bf16*)outv)[o] = __float2bfloat16(v);
          }
          if (!(l16 & 1))
            STA_U32(wp + row * 2048 + col * 2, pack2(v, pv));
        }
      }
      __syncthreads();              // drains each wave's vmcnt before barrier
      if (t == 0) ADDR_I32(c0);     // release: panel LLC-visible before bump
    }
  } else {
    // ===================== h1 cohort: 64 blocks, 16 cols each ==============
    const int n0 = (blk - 32) * 16;
    const char* bXp = sWb + lane * 16;           // Wx1 slice, kt stride 1024
    const char* bHp = sWb + 32768 + lane * 16;   // Wh1 slice
    const float bb = __bfloat162float(bvecB[HID + n0 + l16]);
    for (int s = 0; s < 128; ++s) {
      if (t == 0) {
        while (LDAQ_I32(c0) < 32 * (s + 1)) __builtin_amdgcn_s_sleep(1);
        if (s > 0) while (LDAQ_I32(c1) < 64 * s) __builtin_amdgcn_s_sleep(1);
      }
      __syncthreads();

      const char* aX = H0f + (size_t)((s + 1) & 31) * PNL + (m + l16) * 2048 + quad * 16;
      const char* aH = H1f + (size_t)(s % 3) * PNL + (m + l16) * 2048 + quad * 16;
      floatx4 accX = {}, accH = {};
      #pragma unroll
      for (int half = 0; half < 2; ++half) {
        U16B x[16], h[16];
        #pragma unroll
        for (int i = 0; i < 16; ++i) {
          int kt = half * 16 + i;
          x[i].u[0] = LDA_U64(aX + kt * 64);
          x[i].u[1] = LDA_U64(aX + kt * 64 + 8);
          h[i].u[0] = LDA_U64(aH + kt * 64);
          h[i].u[1] = LDA_U64(aH + kt * 64 + 8);
        }
        #pragma unroll
        for (int i = 0; i < 16; ++i) {
          int kt = half * 16 + i;
          accX = MFMA(x[i].s, *(const short8*)(bXp + kt * 1024), accX);
          accH = MFMA(h[i].s, *(const short8*)(bHp + kt * 1024), accH);
        }
      }

      char* wp = H1f + (size_t)((s + 1) % 3) * PNL;
      #pragma unroll
      for (int r = 0; r < 4; ++r) {
        int row = m + quad * 4 + r, col = n0 + l16;
        float v = tanhf(accX[r] + accH[r] + bb);
        float pv = __shfl_xor(v, 1);
        if (s == 127) {                                          // h_final[1]
          size_t o = (size_t)TAIL + 64 * HID + (size_t)row * HID + col;
          if (f) ((float*)outv)[o] = v;
          else   ((bf16*)outv)[o] = __float2bfloat16(v);
        }
        if (!(l16 & 1)) {
          unsigned int pk = pack2(v, pv);
          STA_U32(wp + row * 2048 + col * 2, pk);
          // H1hist via sc1 too: keeps L2 clean so the release-add's
          // writeback finds nothing dirty (cheap, off critical path).
          STA_U32(H1B + ((size_t)(s * 64 + row) * HID + col) * 2, pk);
        }
      }
      __syncthreads();
      if (t == 0) ADDR_I32(c1);
    }
  }
}

// ---------------------------------------------------------------------------
// logits = H1 @ fcW^T + fcb  -> [8192][10000]. fcW already [V][K].
// ---------------------------------------------------------------------------
__global__ __launch_bounds__(256) void gemm_logits(
    const bf16* __restrict__ H1,    // [8192][HID]
    const bf16* __restrict__ fcW,   // [VOCAB][HID] bf16
    const bf16* __restrict__ fcb,   // [VOCAB] bf16
    void* __restrict__ outv,        // [8192][VOCAB] fp32 or bf16
    const int* __restrict__ flagp)
{
  __shared__ __align__(16) bf16 sA[128 * 32];
  __shared__ __align__(16) bf16 sB[128 * 32];
  int f = *flagp;
  int m0 = blockIdx.x * 128, n0 = blockIdx.y * 128;
  int t = threadIdx.x, lane = t & 63, w = t >> 6;
  int wm = (w >> 1) * 64, wn = (w & 1) * 64;
  int quad = lane >> 4, l16 = lane & 15;

  int r0 = t >> 2, kc = t & 3;
  int rB0 = n0 + r0;      if (rB0 > VOCAB - 1) rB0 = VOCAB - 1;
  int rB1 = n0 + r0 + 64; if (rB1 > VOCAB - 1) rB1 = VOCAB - 1;
  const bf16* ga0 = H1 + (size_t)(m0 + r0) * HID + kc * 8;
  const bf16* ga1 = ga0 + (size_t)64 * HID;
  const bf16* gb0 = fcW + (size_t)rB0 * HID + kc * 8;
  const bf16* gb1 = fcW + (size_t)rB1 * HID + kc * 8;
  bf16* sa0 = sA + t * 8;  bf16* sa1 = sA + (t + 256) * 8;
  bf16* sb0 = sB + t * 8;  bf16* sb1 = sB + (t + 256) * 8;

  floatx4 acc[4][4];
  #pragma unroll
  for (int j = 0; j < 4; ++j) {
    int c = n0 + wn + j * 16 + l16;
    float bv = __bfloat162float(fcb[c > VOCAB - 1 ? VOCAB - 1 : c]);
    #pragma unroll
    for (int i = 0; i < 4; ++i) acc[i][j] = (floatx4){bv, bv, bv, bv};
  }

  for (int kt = 0; kt < 32; ++kt) {
    gl_lds16(ga0, sa0); gl_lds16(ga1, sa1);
    gl_lds16(gb0, sb0); gl_lds16(gb1, sb1);
    ga0 += 32; ga1 += 32; gb0 += 32; gb1 += 32;
    __syncthreads();
    short8 af[4], bfr[4];
    #pragma unroll
    for (int i = 0; i < 4; ++i)
      af[i] = *(const short8*)(sA + (wm + i * 16 + l16) * 32 + quad * 8);
    #pragma unroll
    for (int j = 0; j < 4; ++j)
      bfr[j] = *(const short8*)(sB + (wn + j * 16 + l16) * 32 + quad * 8);
    #pragma unroll
    for (int i = 0; i < 4; ++i)
      #pragma unroll
      for (int j = 0; j < 4; ++j)
        acc[i][j] = MFMA(af[i], bfr[j], acc[i][j]);
    __syncthreads();
  }

  #pragma unroll
  for (int i = 0; i < 4; ++i)
    #pragma unroll
    for (int j = 0; j < 4; ++j)
      #pragma unroll
      for (int r = 0; r < 4; ++r) {
        int row = wm + i * 16 + quad * 4 + r;
        int col = n0 + wn + j * 16 + l16;
        if (col < VOCAB) {
          size_t o = (size_t)(m0 + row) * VOCAB + col;
          if (f) ((float*)outv)[o] = acc[i][j][r];
          else   ((bf16*)outv)[o] = __float2bfloat16(acc[i][j][r]);
        }
      }
}

// ---------------------------------------------------------------------------
extern "C" void kernel_launch(void* const* d_in, const int* in_sizes, int n_in,
                              void* d_out, int out_size, void* d_ws, size_t ws_size,
                              hipStream_t stream)
{
  const int*  tok     = (const int*)d_in[0];   // [128][64]
  const void* hid_raw = d_in[1];               // [2][64][1024]
  const void* emb_raw = d_in[2];               // [10000][1024]
  const void* Wx_raw  = d_in[3];               // [2][1024][1024]
  const void* Wh_raw  = d_in[4];               // [2][1024][1024]
  const void* b_raw   = d_in[5];               // [2][1024]
  const void* fcW_raw = d_in[6];               // [10000][1024]
  const void* fcb_raw = d_in[7];               // [10000]

  char* ws = (char*)d_ws;
  float* A0    = (float*)ws;                       //          0 .. 33,554,432  fp32 8192x1024
  bf16*  Wt    = (bf16*)(ws + 33554432);           // 8,388,608 B: 4x1024x1024 bf16
  bf16*  H1hist= (bf16*)(ws + 41943040);           // 16,777,216 B: 8192x1024 bf16
  char*  H0f   = ws + 58720256;                    // 4,194,304 B: 32-slot panel ring
  char*  H1f   = ws + 62914560;                    //   393,216 B: 3-slot panel ring
  bf16*  shared= (bf16*)(ws + 63307776);           // 20,480,000 B: embB, then fcwB
  bf16*  bvecB = (bf16*)(ws + 83787776);           //     4,096 B
  bf16*  fcbB  = (bf16*)(ws + 83791872);           //    20,000 B
  int*   flag  = (int*)(ws + 83811872);            // [0]=dtype, [1]=c0, [2]=c1

  detect<<<1, 256, 0, stream>>>((const unsigned short*)emb_raw, flag);
  convert_any<<<2048, 256, 0, stream>>>(emb_raw, shared, VOCAB * HID, flag);
  convert_any<<<8,    256, 0, stream>>>(b_raw,   bvecB, 2 * HID, flag);
  convert_any<<<40,   256, 0, stream>>>(fcb_raw, fcbB, VOCAB, flag);
  init_hidden<<<256, 256, 0, stream>>>(hid_raw, (bf16*)H0f, (bf16*)H1f, flag);
  transpose4<<<dim3(16, 16, 4), 256, 0, stream>>>(Wx_raw, Wh_raw, Wt, flag);
  gemm_a0<<<dim3(64, 8), 256, 0, stream>>>(tok, shared, Wt, bvecB, A0);
  // emb no longer needed -> reuse the buffer for fcW (stream-ordered)
  convert_any<<<2048, 256, 0, stream>>>(fcW_raw, shared, VOCAB * HID, flag);
  wavefront_persist<<<96, 256, 0, stream>>>(A0, Wt, bvecB, H0f, H1f,
                                            H1hist, d_out, flag);
  gemm_logits<<<dim3(64, 79), 256, 0, stream>>>(H1hist, shared, fcbB, d_out, flag);
}

// Round 4
// 2695.115 us; speedup vs baseline: 1.1234x; 1.1234x over previous
//
#include <hip/hip_runtime.h>
#include <hip/hip_bf16.h>
#include <math.h>

typedef __hip_bfloat16 bf16;
typedef __attribute__((ext_vector_type(8))) short short8;
typedef __attribute__((ext_vector_type(4))) float floatx4;

#define SEQ   128
#define BATCH 64
#define VOCAB 10000
#define HID   1024
#define TAIL  81920000   // SEQ*BATCH*VOCAB, element offset of h_final in d_out
#define PNL   131072     // one hidden panel: 64 rows * 1024 cols * 2B (bf16)

#define MFMA(a,b,c) __builtin_amdgcn_mfma_f32_16x16x32_bf16((a),(b),(c),0,0,0)

// ALL inter-block traffic uses RELAXED agent-scope atomics: they compile to
// sc0/sc1 LLC-direct loads/stores with ZERO cache-maintenance instructions
// (no buffer_inv, no buffer_wbl2). Visibility is guaranteed because both
// sides bypass the non-coherent L1/L2 tiers. Ordering store->stamp is by
// __syncthreads (s_waitcnt vmcnt(0) before s_barrier drains the sc1 stores).
#define LDA_U64(p)   __hip_atomic_load((const unsigned long long*)(p), __ATOMIC_RELAXED, __HIP_MEMORY_SCOPE_AGENT)
#define LDA_I32(p)   __hip_atomic_load((const int*)(p), __ATOMIC_RELAXED, __HIP_MEMORY_SCOPE_AGENT)
#define STA_U32(p,v) __hip_atomic_store((unsigned int*)(p), (v), __ATOMIC_RELAXED, __HIP_MEMORY_SCOPE_AGENT)
#define STA_I32(p,v) __hip_atomic_store((int*)(p), (v), __ATOMIC_RELAXED, __HIP_MEMORY_SCOPE_AGENT)

union U16B { unsigned long long u[2]; short8 s; };

__device__ inline unsigned int pack2(float lo, float hi) {
  unsigned short a = __builtin_bit_cast(unsigned short, __float2bfloat16(lo));
  unsigned short b = __builtin_bit_cast(unsigned short, __float2bfloat16(hi));
  return ((unsigned int)b << 16) | (unsigned int)a;
}

__device__ inline void gl_lds16(const bf16* g, bf16* s) {
  __builtin_amdgcn_global_load_lds(
      (const __attribute__((address_space(1))) void*)g,
      (__attribute__((address_space(3))) void*)s, 16, 0, 0);
}

// read element i of an input tensor that is either fp32 (f=1) or bf16 (f=0)
__device__ inline float ld_in(const void* p, size_t i, int f) {
  return f ? ((const float*)p)[i] : __bfloat162float(((const bf16*)p)[i]);
}

// ---------------------------------------------------------------------------
// Detect input dtype. flag[0]=1 -> fp32 inputs, 0 -> bf16.
// Zeroes the per-block step-stamp arrays used by the persistent kernel:
//   stamp0 = flag+32   (32 h0 blocks, stride 32 ints = 128B line each)
//   stamp1 = flag+1056 (64 h1 blocks, stride 32 ints)
// ---------------------------------------------------------------------------
__global__ __launch_bounds__(256) void detect(const unsigned short* __restrict__ u,
                                              int* __restrict__ flag) {
  __shared__ int smax;
  if (threadIdx.x == 0) smax = 0;
  __syncthreads();
  int mymax = 0;
  for (int i = threadIdx.x * 2; i < 4096; i += 512) {   // even indices only
    int e = (u[i] >> 7) & 0xFF;
    mymax = max(mymax, e);
  }
  atomicMax(&smax, mymax);
  for (int i = threadIdx.x + 1; i < 3104; i += 256) flag[i] = 0;
  __syncthreads();
  if (threadIdx.x == 0) flag[0] = (smax >= 0xF0) ? 1 : 0;
}

// ---------------------------------------------------------------------------
__global__ __launch_bounds__(256) void convert_any(const void* __restrict__ src,
                                                   bf16* __restrict__ dst, int n,
                                                   const int* __restrict__ flagp) {
  int f = *flagp;
  for (int i = blockIdx.x * 256 + threadIdx.x; i < n; i += gridDim.x * 256)
    dst[i] = __float2bfloat16(ld_in(src, (size_t)i, f));
}

// initial hidden states -> bf16 panels (slot 0 of H0 ring / H1 triple-buffer)
__global__ __launch_bounds__(256) void init_hidden(const void* __restrict__ src,
                                                   bf16* __restrict__ h0,
                                                   bf16* __restrict__ h1,
                                                   const int* __restrict__ flagp) {
  int f = *flagp;
  int i = blockIdx.x * 256 + threadIdx.x;
  if (i < 65536) {
    h0[i] = __float2bfloat16(ld_in(src, (size_t)i, f));
    h1[i] = __float2bfloat16(ld_in(src, (size_t)(65536 + i), f));
  }
}

// ---------------------------------------------------------------------------
// Transpose the 4 recurrence weight matrices into bf16 [n][k] (K-contiguous).
// Wt layout: z=0 Wx0^T, z=1 Wh0^T, z=2 Wx1^T, z=3 Wh1^T (each 1024x1024).
// ---------------------------------------------------------------------------
__global__ __launch_bounds__(256) void transpose4(const void* __restrict__ Wx,
                                                  const void* __restrict__ Wh,
                                                  bf16* __restrict__ Wt,
                                                  const int* __restrict__ flagp) {
  __shared__ bf16 tile[64][65];
  int f = *flagp;
  int z = blockIdx.z;
  const void* src = (z & 1) ? Wh : Wx;
  size_t loff = (z >> 1) ? (size_t)HID * HID : 0;
  bf16* dst = Wt + (size_t)z * HID * HID;
  int r0 = blockIdx.x * 64, c0 = blockIdx.y * 64;
  int t = threadIdx.x, cc = t & 63, rg = t >> 6;
  #pragma unroll
  for (int i = 0; i < 16; ++i) {
    int r = rg * 16 + i;
    tile[r][cc] = __float2bfloat16(ld_in(src, loff + (size_t)(r0 + r) * HID + c0 + cc, f));
  }
  __syncthreads();
  #pragma unroll
  for (int i = 0; i < 16; ++i) {
    int j = rg * 16 + i;
    dst[(size_t)(c0 + j) * HID + r0 + cc] = tile[cc][j];  // dst[j][k]=src[k][j]
  }
}

// ---------------------------------------------------------------------------
// A0 = emb[tok] @ Wx0 + b0   (fp32 out, [8192][1024]).  m97-style 128x128x32.
// ---------------------------------------------------------------------------
__global__ __launch_bounds__(256) void gemm_a0(
    const int*  __restrict__ tok,    // [8192]
    const bf16* __restrict__ emb,    // [VOCAB][HID] bf16
    const bf16* __restrict__ Wx0t,   // [HID][HID]  (n,k)
    const bf16* __restrict__ b0,     // [HID] bf16
    float* __restrict__ A0)          // [8192][HID]
{
  __shared__ __align__(16) bf16 sA[128 * 32];
  __shared__ __align__(16) bf16 sB[128 * 32];
  int m0 = blockIdx.x * 128, n0 = blockIdx.y * 128;
  int t = threadIdx.x, lane = t & 63, w = t >> 6;
  int wm = (w >> 1) * 64, wn = (w & 1) * 64;
  int quad = lane >> 4, l16 = lane & 15;

  int r0 = t >> 2, kc = t & 3;
  const bf16* ga0 = emb + (size_t)tok[m0 + r0] * HID + kc * 8;
  const bf16* ga1 = emb + (size_t)tok[m0 + r0 + 64] * HID + kc * 8;
  const bf16* gb0 = Wx0t + (size_t)(n0 + r0) * HID + kc * 8;
  const bf16* gb1 = gb0 + (size_t)64 * HID;
  bf16* sa0 = sA + t * 8;  bf16* sa1 = sA + (t + 256) * 8;
  bf16* sb0 = sB + t * 8;  bf16* sb1 = sB + (t + 256) * 8;

  floatx4 acc[4][4];
  #pragma unroll
  for (int j = 0; j < 4; ++j) {
    float bv = __bfloat162float(b0[n0 + wn + j * 16 + l16]);
    #pragma unroll
    for (int i = 0; i < 4; ++i) acc[i][j] = (floatx4){bv, bv, bv, bv};
  }

  for (int kt = 0; kt < 32; ++kt) {
    gl_lds16(ga0, sa0); gl_lds16(ga1, sa1);
    gl_lds16(gb0, sb0); gl_lds16(gb1, sb1);
    ga0 += 32; ga1 += 32; gb0 += 32; gb1 += 32;
    __syncthreads();
    short8 af[4], bfr[4];
    #pragma unroll
    for (int i = 0; i < 4; ++i)
      af[i] = *(const short8*)(sA + (wm + i * 16 + l16) * 32 + quad * 8);
    #pragma unroll
    for (int j = 0; j < 4; ++j)
      bfr[j] = *(const short8*)(sB + (wn + j * 16 + l16) * 32 + quad * 8);
    #pragma unroll
    for (int i = 0; i < 4; ++i)
      #pragma unroll
      for (int j = 0; j < 4; ++j)
        acc[i][j] = MFMA(af[i], bfr[j], acc[i][j]);
    __syncthreads();
  }

  #pragma unroll
  for (int i = 0; i < 4; ++i)
    #pragma unroll
    for (int j = 0; j < 4; ++j)
      #pragma unroll
      for (int r = 0; r < 4; ++r) {
        int row = wm + i * 16 + quad * 4 + r;
        int col = wn + j * 16 + l16;
        A0[(size_t)(m0 + row) * HID + n0 + col] = acc[i][j][r];
      }
}

// ---------------------------------------------------------------------------
// Persistent wavefront, zero-cache-op zero-RMW sync:
//   blocks  0..31 (h0, N=32): h0[k] = tanh(A0[k] + h0[k-1] @ Wh0)
//   blocks 32..95 (h1, N=16): h1[s] = tanh(h0[s]@Wx1 + h1[s-1]@Wh1 + b1)
// Panels exchanged via relaxed sc1 stores/loads (LLC-direct). Each block
// publishes progress by STORING k+1 to its private 128B stamp line after a
// __syncthreads (which drains vmcnt -> panel stores are LLC-acked first).
// Waiters poll all producer stamps in parallel (one lane per stamp) with
// __all() -- no atomicRMW, no acquire/release, no buffer_inv/wbl2 anywhere.
// ---------------------------------------------------------------------------
__global__ __launch_bounds__(256) void wavefront_persist(
    const float* __restrict__ A0,
    const bf16* __restrict__ Wt,      // 4x[1024][1024]: Wx0t,Wh0t,Wx1t,Wh1t
    const bf16* __restrict__ bvecB,   // [2*HID] bf16
    char* __restrict__ H0f,           // 32-slot ring of bf16 panels [64][1024]
    char* __restrict__ H1f,           // 3-slot ring of bf16 panels
    bf16* __restrict__ H1hist,        // [8192][HID] bf16 (for gemm_logits)
    void* __restrict__ outv,
    int* __restrict__ flagp)          // [0]=dtype, +32 stamp0[32], +1056 stamp1[64]
{
  __shared__ short8 sW8[4096];        // 64 KB weight slice, MFMA-native layout
  char* sWb = (char*)sW8;
  const int f = flagp[0];
  int* stamp0 = flagp + 32;           // stride 32 ints (128B) per block
  int* stamp1 = flagp + 1056;
  char* H1B = (char*)H1hist;
  const int blk = blockIdx.x;
  const int t = threadIdx.x, lane = t & 63, w = t >> 6;
  const int quad = lane >> 4, l16 = lane & 15;
  const int m = w * 16;               // wave w: rows m..m+15
  const bool isH1 = blk >= 32;
  const int* sp0 = stamp0 + (lane & 31) * 32;   // lane-parallel poll targets
  const int* sp1 = stamp1 + lane * 32;

  const bf16* Wh0t = Wt + (size_t)1 * HID * HID;
  const bf16* Wx1t = Wt + (size_t)2 * HID * HID;
  const bf16* Wh1t = Wt + (size_t)3 * HID * HID;

  // ---- one-time LDS staging of this block's weight slice(s) ----
  if (!isH1) {
    const int n0 = blk * 32;          // 32 rows of Wh0^T
    #pragma unroll
    for (int i = 0; i < 16; ++i) {
      int idx = i * 256 + t;          // 0..4095
      int row = idx >> 7, c16 = idx & 127;
      short8 v = *(const short8*)(Wh0t + (size_t)(n0 + row) * HID + c16 * 8);
      int off = (c16 >> 2) * 2048 + (row >> 4) * 1024 + (c16 & 3) * 256 + (row & 15) * 16;
      *(short8*)(sWb + off) = v;
    }
  } else {
    const int n0 = (blk - 32) * 16;   // 16 rows each of Wx1^T, Wh1^T
    #pragma unroll
    for (int i = 0; i < 8; ++i) {
      int idx = i * 256 + t;          // 0..2047
      int row = idx >> 7, c16 = idx & 127;
      int off = (c16 >> 2) * 1024 + (c16 & 3) * 256 + (row & 15) * 16;
      *(short8*)(sWb + off)         = *(const short8*)(Wx1t + (size_t)(n0 + row) * HID + c16 * 8);
      *(short8*)(sWb + 32768 + off) = *(const short8*)(Wh1t + (size_t)(n0 + row) * HID + c16 * 8);
    }
  }
  __syncthreads();

  if (!isH1) {
    // ===================== h0 cohort: 32 blocks, 32 cols each ==============
    const int n0 = blk * 32;
    int* mystamp = stamp0 + blk * 32;
    const char* b0p = sWb + lane * 16;          // j=0 cols, kt stride 2048
    const char* b1p = sWb + 1024 + lane * 16;   // j=1 cols
    for (int k = 0; k < 128; ++k) {
      // all-lane parallel poll: all h0 stamps >= k, and (ring guard) all h1
      // stamps >= k-31. Bounded: converts any bug into wrong-answer, not hang.
      if (k > 0)
        for (int g = 0; !__all(LDA_I32(sp0) >= k) && g < (1 << 26); ++g)
          __builtin_amdgcn_s_sleep(1);
      if (k >= 32)
        for (int g = 0; !__all(LDA_I32(sp1) >= k - 31) && g < (1 << 26); ++g)
          __builtin_amdgcn_s_sleep(1);

      // batch-issue all 64 A-fragment loads (LLC, sc1); then A0 addends
      const char* aB = H0f + (size_t)(k & 31) * PNL + (m + l16) * 2048 + quad * 16;
      U16B a[32];
      #pragma unroll
      for (int kt = 0; kt < 32; ++kt) {
        a[kt].u[0] = LDA_U64(aB + kt * 64);
        a[kt].u[1] = LDA_U64(aB + kt * 64 + 8);
      }
      float a0r[2][4];
      #pragma unroll
      for (int j = 0; j < 2; ++j)
        #pragma unroll
        for (int r = 0; r < 4; ++r)
          a0r[j][r] = A0[(size_t)(k * 64 + m + quad * 4 + r) * HID + n0 + j * 16 + l16];

      floatx4 acc0 = {}, acc1 = {};
      #pragma unroll
      for (int kt = 0; kt < 32; ++kt) {
        acc0 = MFMA(a[kt].s, *(const short8*)(b0p + kt * 2048), acc0);
        acc1 = MFMA(a[kt].s, *(const short8*)(b1p + kt * 2048), acc1);
      }

      // epilogue: tanh, pack bf16 pairs, write-through to H0f ring slot k+1
      char* wp = H0f + (size_t)((k + 1) & 31) * PNL;
      #pragma unroll
      for (int j = 0; j < 2; ++j) {
        floatx4 ac = j ? acc1 : acc0;
        #pragma unroll
        for (int r = 0; r < 4; ++r) {
          int row = m + quad * 4 + r, col = n0 + j * 16 + l16;
          float v = tanhf(ac[r] + a0r[j][r]);
          float pv = __shfl_xor(v, 1);
          if (k == 127) {                                        // h_final[0]
            size_t o = (size_t)TAIL + (size_t)row * HID + col;
            if (f) ((float*)outv)[o] = v;
            else   ((bf16*)outv)[o] = __float2bfloat16(v);
          }
          if (!(l16 & 1))
            STA_U32(wp + row * 2048 + col * 2, pack2(v, pv));
        }
      }
      __syncthreads();                   // drains vmcnt: panel stores LLC-acked
      if (t == 0) STA_I32(mystamp, k + 1);   // publish (store-only, no RMW)
    }
  } else {
    // ===================== h1 cohort: 64 blocks, 16 cols each ==============
    const int n0 = (blk - 32) * 16;
    int* mystamp = stamp1 + (blk - 32) * 32;
    const char* bXp = sWb + lane * 16;           // Wx1 slice, kt stride 1024
    const char* bHp = sWb + 32768 + lane * 16;   // Wh1 slice
    const float bb = __bfloat162float(bvecB[HID + n0 + l16]);
    for (int s = 0; s < 128; ++s) {
      for (int g = 0; !__all(LDA_I32(sp0) >= s + 1) && g < (1 << 26); ++g)
        __builtin_amdgcn_s_sleep(1);
      if (s > 0)
        for (int g = 0; !__all(LDA_I32(sp1) >= s) && g < (1 << 26); ++g)
          __builtin_amdgcn_s_sleep(1);

      const char* aX = H0f + (size_t)((s + 1) & 31) * PNL + (m + l16) * 2048 + quad * 16;
      const char* aH = H1f + (size_t)(s % 3) * PNL + (m + l16) * 2048 + quad * 16;
      floatx4 accX = {}, accH = {};
      #pragma unroll
      for (int half = 0; half < 2; ++half) {
        U16B x[16], h[16];
        #pragma unroll
        for (int i = 0; i < 16; ++i) {
          int kt = half * 16 + i;
          x[i].u[0] = LDA_U64(aX + kt * 64);
          x[i].u[1] = LDA_U64(aX + kt * 64 + 8);
          h[i].u[0] = LDA_U64(aH + kt * 64);
          h[i].u[1] = LDA_U64(aH + kt * 64 + 8);
        }
        #pragma unroll
        for (int i = 0; i < 16; ++i) {
          int kt = half * 16 + i;
          accX = MFMA(x[i].s, *(const short8*)(bXp + kt * 1024), accX);
          accH = MFMA(h[i].s, *(const short8*)(bHp + kt * 1024), accH);
        }
      }

      char* wp = H1f + (size_t)((s + 1) % 3) * PNL;
      #pragma unroll
      for (int r = 0; r < 4; ++r) {
        int row = m + quad * 4 + r, col = n0 + l16;
        float v = tanhf(accX[r] + accH[r] + bb);
        float pv = __shfl_xor(v, 1);
        if (s == 127) {                                          // h_final[1]
          size_t o = (size_t)TAIL + 64 * HID + (size_t)row * HID + col;
          if (f) ((float*)outv)[o] = v;
          else   ((bf16*)outv)[o] = __float2bfloat16(v);
        }
        if (!(l16 & 1)) {
          unsigned int pk = pack2(v, pv);
          STA_U32(wp + row * 2048 + col * 2, pk);
          STA_U32(H1B + ((size_t)(s * 64 + row) * HID + col) * 2, pk);
        }
      }
      __syncthreads();
      if (t == 0) STA_I32(mystamp, s + 1);
    }
  }
}

// ---------------------------------------------------------------------------
// logits = H1 @ fcW^T + fcb  -> [8192][10000]. fcW already [V][K].
// ---------------------------------------------------------------------------
__global__ __launch_bounds__(256) void gemm_logits(
    const bf16* __restrict__ H1,    // [8192][HID]
    const bf16* __restrict__ fcW,   // [VOCAB][HID] bf16
    const bf16* __restrict__ fcb,   // [VOCAB] bf16
    void* __restrict__ outv,        // [8192][VOCAB] fp32 or bf16
    const int* __restrict__ flagp)
{
  __shared__ __align__(16) bf16 sA[128 * 32];
  __shared__ __align__(16) bf16 sB[128 * 32];
  int f = *flagp;
  int m0 = blockIdx.x * 128, n0 = blockIdx.y * 128;
  int t = threadIdx.x, lane = t & 63, w = t >> 6;
  int wm = (w >> 1) * 64, wn = (w & 1) * 64;
  int quad = lane >> 4, l16 = lane & 15;

  int r0 = t >> 2, kc = t & 3;
  int rB0 = n0 + r0;      if (rB0 > VOCAB - 1) rB0 = VOCAB - 1;
  int rB1 = n0 + r0 + 64; if (rB1 > VOCAB - 1) rB1 = VOCAB - 1;
  const bf16* ga0 = H1 + (size_t)(m0 + r0) * HID + kc * 8;
  const bf16* ga1 = ga0 + (size_t)64 * HID;
  const bf16* gb0 = fcW + (size_t)rB0 * HID + kc * 8;
  const bf16* gb1 = fcW + (size_t)rB1 * HID + kc * 8;
  bf16* sa0 = sA + t * 8;  bf16* sa1 = sA + (t + 256) * 8;
  bf16* sb0 = sB + t * 8;  bf16* sb1 = sB + (t + 256) * 8;

  floatx4 acc[4][4];
  #pragma unroll
  for (int j = 0; j < 4; ++j) {
    int c = n0 + wn + j * 16 + l16;
    float bv = __bfloat162float(fcb[c > VOCAB - 1 ? VOCAB - 1 : c]);
    #pragma unroll
    for (int i = 0; i < 4; ++i) acc[i][j] = (floatx4){bv, bv, bv, bv};
  }

  for (int kt = 0; kt < 32; ++kt) {
    gl_lds16(ga0, sa0); gl_lds16(ga1, sa1);
    gl_lds16(gb0, sb0); gl_lds16(gb1, sb1);
    ga0 += 32; ga1 += 32; gb0 += 32; gb1 += 32;
    __syncthreads();
    short8 af[4], bfr[4];
    #pragma unroll
    for (int i = 0; i < 4; ++i)
      af[i] = *(const short8*)(sA + (wm + i * 16 + l16) * 32 + quad * 8);
    #pragma unroll
    for (int j = 0; j < 4; ++j)
      bfr[j] = *(const short8*)(sB + (wn + j * 16 + l16) * 32 + quad * 8);
    #pragma unroll
    for (int i = 0; i < 4; ++i)
      #pragma unroll
      for (int j = 0; j < 4; ++j)
        acc[i][j] = MFMA(af[i], bfr[j], acc[i][j]);
    __syncthreads();
  }

  #pragma unroll
  for (int i = 0; i < 4; ++i)
    #pragma unroll
    for (int j = 0; j < 4; ++j)
      #pragma unroll
      for (int r = 0; r < 4; ++r) {
        int row = wm + i * 16 + quad * 4 + r;
        int col = n0 + wn + j * 16 + l16;
        if (col < VOCAB) {
          size_t o = (size_t)(m0 + row) * VOCAB + col;
          if (f) ((float*)outv)[o] = acc[i][j][r];
          else   ((bf16*)outv)[o] = __float2bfloat16(acc[i][j][r]);
        }
      }
}

// ---------------------------------------------------------------------------
extern "C" void kernel_launch(void* const* d_in, const int* in_sizes, int n_in,
                              void* d_out, int out_size, void* d_ws, size_t ws_size,
                              hipStream_t stream)
{
  const int*  tok     = (const int*)d_in[0];   // [128][64]
  const void* hid_raw = d_in[1];               // [2][64][1024]
  const void* emb_raw = d_in[2];               // [10000][1024]
  const void* Wx_raw  = d_in[3];               // [2][1024][1024]
  const void* Wh_raw  = d_in[4];               // [2][1024][1024]
  const void* b_raw   = d_in[5];               // [2][1024]
  const void* fcW_raw = d_in[6];               // [10000][1024]
  const void* fcb_raw = d_in[7];               // [10000]

  char* ws = (char*)d_ws;
  float* A0    = (float*)ws;                       //          0 .. 33,554,432  fp32 8192x1024
  bf16*  Wt    = (bf16*)(ws + 33554432);           // 8,388,608 B: 4x1024x1024 bf16
  bf16*  H1hist= (bf16*)(ws + 41943040);           // 16,777,216 B: 8192x1024 bf16
  char*  H0f   = ws + 58720256;                    // 4,194,304 B: 32-slot panel ring
  char*  H1f   = ws + 62914560;                    //   393,216 B: 3-slot panel ring
  bf16*  shared= (bf16*)(ws + 63307776);           // 20,480,000 B: embB, then fcwB
  bf16*  bvecB = (bf16*)(ws + 83787776);           //     4,096 B
  bf16*  fcbB  = (bf16*)(ws + 83791872);           //    20,000 B
  int*   flag  = (int*)(ws + 83811872);            // [0]=dtype, +32/+1056 stamps

  detect<<<1, 256, 0, stream>>>((const unsigned short*)emb_raw, flag);
  convert_any<<<2048, 256, 0, stream>>>(emb_raw, shared, VOCAB * HID, flag);
  convert_any<<<8,    256, 0, stream>>>(b_raw,   bvecB, 2 * HID, flag);
  convert_any<<<40,   256, 0, stream>>>(fcb_raw, fcbB, VOCAB, flag);
  init_hidden<<<256, 256, 0, stream>>>(hid_raw, (bf16*)H0f, (bf16*)H1f, flag);
  transpose4<<<dim3(16, 16, 4), 256, 0, stream>>>(Wx_raw, Wh_raw, Wt, flag);
  gemm_a0<<<dim3(64, 8), 256, 0, stream>>>(tok, shared, Wt, bvecB, A0);
  // emb no longer needed -> reuse the buffer for fcW (stream-ordered)
  convert_any<<<2048, 256, 0, stream>>>(fcW_raw, shared, VOCAB * HID, flag);
  wavefront_persist<<<96, 256, 0, stream>>>(A0, Wt, bvecB, H0f, H1f,
                                            H1hist, d_out, flag);
  gemm_logits<<<dim3(64, 79), 256, 0, stream>>>(H1hist, shared, fcbB, d_out, flag);
}